// Round 18
// baseline (229.785 us; speedup 1.0000x reference)
//
#include <hip/hip_runtime.h>

#define N_PTS   65536
#define PBLK    32                 // points per block
#define NBLK    (N_PTS / PBLK)     // 2048 blocks
#define HID     256
#define NCH     4                  // v, p=gx+gy, m=gx-gy, h=hxx+hyy

typedef __attribute__((ext_vector_type(16))) float floatx16;  // 32x32 MFMA C/D
typedef __attribute__((ext_vector_type(4)))  float floatx4;
typedef __attribute__((ext_vector_type(8)))  int   int8v;     // 32-byte fp8 frag
typedef __attribute__((ext_vector_type(4)))  long long llx4;  // 32-byte as 4x b64
typedef __attribute__((ext_vector_type(2)))  unsigned uint2v;

// Pade(3,2)+clamp tanh: 5 VALU + 1 TRANS. |err| <= ~7e-4 abs; exact saturation.
__device__ __forceinline__ float fast_tanh(float x) {
    float x2  = x * x;
    float num = x * (27.0f + x2);
    float den = 27.0f + 9.0f * x2;
    float r   = num * __builtin_amdgcn_rcpf(den);
    return fminf(fmaxf(r, -1.0f), 1.0f);   // -> v_med3_f32
}
__device__ __forceinline__ floatx4 tanh4(floatx4 z) {
    floatx4 r;
    r.x = fast_tanh(z.x); r.y = fast_tanh(z.y);
    r.z = fast_tanh(z.z); r.w = fast_tanh(z.w);
    return r;
}
// pack 4 f32 -> 4 fp8(e4m3) in one 32-bit word (2 cvt_pk instrs)
__device__ __forceinline__ unsigned pk4_fp8(floatx4 v) {
    unsigned w = __builtin_amdgcn_cvt_pk_fp8_f32(v.x, v.y, 0, false);
    w = __builtin_amdgcn_cvt_pk_fp8_f32(v.z, v.w, (int)w, true);
    return w;
}
__device__ __forceinline__ unsigned pk4_fp8s(float a, float b, float c, float d) {
    unsigned w = __builtin_amdgcn_cvt_pk_fp8_f32(a, b, 0, false);
    w = __builtin_amdgcn_cvt_pk_fp8_f32(c, d, (int)w, true);
    return w;
}

// ---- weight transpose+convert: Wt[L][n][k] = fp8(W_L[k][n]) ----
__global__ __launch_bounds__(64) void conv_w(
    const float* __restrict__ W1, const float* __restrict__ W2,
    const float* __restrict__ W3, const float* __restrict__ W4,
    unsigned char* __restrict__ Wt)
{
    int layer = blockIdx.x >> 8;
    int n     = blockIdx.x & 255;
    const float* W = (layer == 0) ? W1 : (layer == 1) ? W2 : (layer == 2) ? W3 : W4;
    int t = threadIdx.x;                      // word index: k = 4t..4t+3
    float a = W[(t * 4 + 0) * 256 + n];
    float b = W[(t * 4 + 1) * 256 + n];
    float c = W[(t * 4 + 2) * 256 + n];
    float d = W[(t * 4 + 3) * 256 + n];
    ((unsigned*)Wt)[((layer << 8) + n) * 64 + t] = pk4_fp8s(a, b, c, d);
}

__global__ __launch_bounds__(512, 4) void pinn_main(
    const float* __restrict__ vect, const int* __restrict__ vals,
    const float* __restrict__ W0, const float* __restrict__ b0,
    const float* __restrict__ b1, const float* __restrict__ b2,
    const float* __restrict__ b3, const float* __restrict__ b4,
    const float* __restrict__ W5, const float* __restrict__ b5,
    const unsigned char* __restrict__ Wt, float* __restrict__ partials)
{
    // Hs[buf][ch][pt][k] fp8: byte = buf*32768 + ch*8192 + pt*256 + (k ^ ((pt&15)<<3))
    __shared__ __align__(16) unsigned char Hs[2][NCH][PBLK][HID];   // 64 KB
    __shared__ float redT[8][PBLK];   // per-wave partial T dot
    __shared__ float redR[8][PBLK];   // per-wave partial R dot

    const int tid   = threadIdx.x;
    const int wave  = tid >> 6;
    const int lane  = tid & 63;
    const int pt    = lane & 31;          // MFMA column = point / A row
    const int hi    = lane >> 5;
    const int pbase = blockIdx.x * PBLK;
    const int swz   = (pt & 15) << 3;     // 8B-granular XOR swizzle (2-way = free)

    // ---------------- layer 0: 2 -> 256 (fp32 VALU) ----------------
    {
        const int p0 = tid & 31;          // point
        const int c0 = (tid >> 5) * 16;   // 16 neurons per thread
        const int sz = (p0 & 15) << 3;
        float x = vect[(pbase + p0) * 2 + 0];
        float y = vect[(pbase + p0) * 2 + 1];
        #pragma unroll
        for (int jj = 0; jj < 2; ++jj) {
            const int cb = c0 + jj * 8;
            float4 wxa = *(const float4*)(W0 + cb);
            float4 wxb = *(const float4*)(W0 + cb + 4);
            float4 wya = *(const float4*)(W0 + HID + cb);
            float4 wyb = *(const float4*)(W0 + HID + cb + 4);
            float4 bba = *(const float4*)(b0 + cb);
            float4 bbb = *(const float4*)(b0 + cb + 4);
            float wx[8] = {wxa.x, wxa.y, wxa.z, wxa.w, wxb.x, wxb.y, wxb.z, wxb.w};
            float wy[8] = {wya.x, wya.y, wya.z, wya.w, wyb.x, wyb.y, wyb.z, wyb.w};
            float bb[8] = {bba.x, bba.y, bba.z, bba.w, bbb.x, bbb.y, bbb.z, bbb.w};
            float av[8], pv[8], mv[8], hv[8];
            #pragma unroll
            for (int q = 0; q < 8; ++q) {
                float z  = x * wx[q] + y * wy[q] + bb[q];
                float a  = fast_tanh(z);
                float s  = 1.0f - a * a;
                float gx = s * wx[q];
                float gy = s * wy[q];
                av[q] = a;
                pv[q] = gx + gy;
                mv[q] = gx - gy;
                hv[q] = -2.0f * a * (gx * wx[q] + gy * wy[q]);
            }
            const int idx = p0 * 256 + (cb ^ sz);
            *(uint2v*)&Hs[0][0][0][idx] = (uint2v){pk4_fp8s(av[0],av[1],av[2],av[3]),
                                                   pk4_fp8s(av[4],av[5],av[6],av[7])};
            *(uint2v*)&Hs[0][1][0][idx] = (uint2v){pk4_fp8s(pv[0],pv[1],pv[2],pv[3]),
                                                   pk4_fp8s(pv[4],pv[5],pv[6],pv[7])};
            *(uint2v*)&Hs[0][2][0][idx] = (uint2v){pk4_fp8s(mv[0],mv[1],mv[2],mv[3]),
                                                   pk4_fp8s(mv[4],mv[5],mv[6],mv[7])};
            *(uint2v*)&Hs[0][3][0][idx] = (uint2v){pk4_fp8s(hv[0],hv[1],hv[2],hv[3]),
                                                   pk4_fp8s(hv[4],hv[5],hv[6],hv[7])};
        }
    }
    __syncthreads();

    // ---------------- hidden layers 1..3: MX-scaled 32x32x64 fp8 MFMA ----------------
    const float* bs[3] = {b1, b2, b3};

    floatx16 zk = (floatx16)(0.0f);       // zero C-operand, init once

    #pragma unroll
    for (int L = 0; L < 3; ++L) {
        const int cur = L & 1;
        const int nxt = cur ^ 1;
        floatx16 acc[NCH];

        const unsigned char* wb = Wt + L * 65536 + (((wave << 5) + pt) << 8) + (hi << 5);
        const unsigned char* hb = &Hs[cur][0][pt][0];     // ch stride 8192

        __builtin_amdgcn_s_setprio(1);
        #pragma unroll
        for (int ks4 = 0; ks4 < 4; ++ks4) {
            const int kb = ks4 * 64 + (hi << 5);
            int8v af = *(const int8v*)(wb + ks4 * 64);    // direct 32B load
            const unsigned char* a0 = hb + ((kb +  0) ^ swz);
            const unsigned char* a1 = hb + ((kb +  8) ^ swz);
            const unsigned char* a2 = hb + ((kb + 16) ^ swz);
            const unsigned char* a3 = hb + ((kb + 24) ^ swz);
            #pragma unroll
            for (int ch = 0; ch < NCH; ++ch) {
                const int co = ch * 8192;
                llx4 t;
                t[0] = *(const long long*)(a0 + co);
                t[1] = *(const long long*)(a1 + co);
                t[2] = *(const long long*)(a2 + co);
                t[3] = *(const long long*)(a3 + co);
                int8v bfv = __builtin_bit_cast(int8v, t);
                acc[ch] = __builtin_amdgcn_mfma_scale_f32_32x32x64_f8f6f4(
                    af, bfv, (ks4 == 0) ? zk : acc[ch], 0, 0, 0, 0x7F, 0, 0x7F);
            }
        }
        __builtin_amdgcn_s_setprio(0);

        // epilogue (writes go to the other buffer; single barrier per layer)
        unsigned char* hw = &Hs[nxt][0][pt][0];
        #pragma unroll
        for (int q = 0; q < 4; ++q) {
            const int nq = (wave << 5) + q * 8 + hi * 4;
            floatx4 bb = *(const floatx4*)(bs[L] + nq);
            floatx4 z, zp, zm, zh;
            #pragma unroll
            for (int r = 0; r < 4; ++r) {
                const int reg = q * 4 + r;
                z[r]  = acc[0][reg];
                zp[r] = acc[1][reg];
                zm[r] = acc[2][reg];
                zh[r] = acc[3][reg];
            }
            z += bb;
            floatx4 a  = tanh4(z);
            floatx4 s  = 1.0f - a * a;
            floatx4 pv = s * zp;
            floatx4 mv = s * zm;
            floatx4 hv = s * (zh - a * (zp * zp + zm * zm));
            const int kk = nq ^ swz;
            *(unsigned*)(hw + 0 * 8192 + kk) = pk4_fp8(a);
            *(unsigned*)(hw + 1 * 8192 + kk) = pk4_fp8(pv);
            *(unsigned*)(hw + 2 * 8192 + kk) = pk4_fp8(mv);
            *(unsigned*)(hw + 3 * 8192 + kk) = pk4_fp8(hv);
        }
        __syncthreads();   // one barrier per layer
    }

    // ---------------- layer 4 (peeled): MFMA + FUSED final-layer dot ----------------
    {
        floatx16 acc[NCH];
        const unsigned char* wb = Wt + 3 * 65536 + (((wave << 5) + pt) << 8) + (hi << 5);
        const unsigned char* hb = &Hs[1][0][pt][0];       // cur = 3&1 = 1

        __builtin_amdgcn_s_setprio(1);
        #pragma unroll
        for (int ks4 = 0; ks4 < 4; ++ks4) {
            const int kb = ks4 * 64 + (hi << 5);
            int8v af = *(const int8v*)(wb + ks4 * 64);
            const unsigned char* a0 = hb + ((kb +  0) ^ swz);
            const unsigned char* a1 = hb + ((kb +  8) ^ swz);
            const unsigned char* a2 = hb + ((kb + 16) ^ swz);
            const unsigned char* a3 = hb + ((kb + 24) ^ swz);
            #pragma unroll
            for (int ch = 0; ch < NCH; ++ch) {
                const int co = ch * 8192;
                llx4 t;
                t[0] = *(const long long*)(a0 + co);
                t[1] = *(const long long*)(a1 + co);
                t[2] = *(const long long*)(a2 + co);
                t[3] = *(const long long*)(a3 + co);
                int8v bfv = __builtin_bit_cast(int8v, t);
                acc[ch] = __builtin_amdgcn_mfma_scale_f32_32x32x64_f8f6f4(
                    af, bfv, (ks4 == 0) ? zk : acc[ch], 0, 0, 0, 0x7F, 0, 0x7F);
            }
        }
        __builtin_amdgcn_s_setprio(0);

        // fused epilogue, scalar-wise to minimize live registers (spill fix):
        float sT = 0.f, sR = 0.f;
        #pragma unroll
        for (int q = 0; q < 4; ++q) {
            const int nq = (wave << 5) + q * 8 + hi * 4;
            floatx4 bb = *(const floatx4*)(b4 + nq);
            floatx4 w5 = *(const floatx4*)(W5 + nq);
            #pragma unroll
            for (int r = 0; r < 4; ++r) {
                const int reg = q * 4 + r;
                float z  = acc[0][reg] + bb[r];
                float a  = fast_tanh(z);
                float s  = 1.0f - a * a;
                float zp = acc[1][reg];
                float zm = acc[2][reg];
                float hv = s * (acc[3][reg] - a * (zp * zp + zm * zm));
                sT = fmaf(a,  w5[r], sT);
                sR = fmaf(hv, w5[r], sR);
            }
        }
        // combine hi=0 / hi=1 halves (lanes pt and pt+32)
        sT += __shfl_down(sT, 32, 64);
        sR += __shfl_down(sR, 32, 64);
        if (lane < 32) {
            redT[wave][lane] = sT;
            redR[wave][lane] = sR;
        }
    }
    __syncthreads();

    // ---------------- loss terms (wave 0) ----------------
    if (wave == 0) {
        const int p32 = lane & 31;
        float r0 = 0.f, r1 = 0.f, r2 = 0.f, r3 = 0.f, r4 = 0.f;
        if (lane < 32) {
            float T = b5[0];
            float R = 0.f;
            #pragma unroll
            for (int w = 0; w < 8; ++w) {
                T += redT[w][p32];
                R += redR[w][p32];
            }
            r0 = R * R;
            int m = vals[pbase + p32];
            if (m == 1)      { float d = T - 1200.0f; r1 = d * d; r2 = 1.0f; }
            else if (m == 2) { float d = T - 25.0f;   r3 = d * d; r4 = 1.0f; }
        }
        #pragma unroll
        for (int off = 32; off > 0; off >>= 1) {
            r0 += __shfl_down(r0, off, 64);
            r1 += __shfl_down(r1, off, 64);
            r2 += __shfl_down(r2, off, 64);
            r3 += __shfl_down(r3, off, 64);
            r4 += __shfl_down(r4, off, 64);
        }
        if (lane == 0) {
            partials[blockIdx.x * 5 + 0] = r0;
            partials[blockIdx.x * 5 + 1] = r1;
            partials[blockIdx.x * 5 + 2] = r2;
            partials[blockIdx.x * 5 + 3] = r3;
            partials[blockIdx.x * 5 + 4] = r4;
        }
    }
}

__global__ __launch_bounds__(256) void pinn_reduce(const float* __restrict__ p,
                                                   float* __restrict__ out)
{
    float s[5] = {0.f, 0.f, 0.f, 0.f, 0.f};
    for (int idx = threadIdx.x; idx < NBLK; idx += 256) {
        #pragma unroll
        for (int c = 0; c < 5; ++c) s[c] += p[idx * 5 + c];
    }
    #pragma unroll
    for (int c = 0; c < 5; ++c) {
        #pragma unroll
        for (int off = 32; off > 0; off >>= 1)
            s[c] += __shfl_down(s[c], off, 64);
    }
    __shared__ float r[4][5];
    int wave = threadIdx.x >> 6;
    int lane = threadIdx.x & 63;
    if (lane == 0) {
        #pragma unroll
        for (int c = 0; c < 5; ++c) r[wave][c] = s[c];
    }
    __syncthreads();
    if (threadIdx.x == 0) {
        float t[5];
        #pragma unroll
        for (int c = 0; c < 5; ++c) t[c] = r[0][c] + r[1][c] + r[2][c] + r[3][c];
        out[0] = t[0] / (float)N_PTS
               + t[1] / fmaxf(t[2], 1.0f)
               + t[3] / fmaxf(t[4], 1.0f);
    }
}

extern "C" void kernel_launch(void* const* d_in, const int* in_sizes, int n_in,
                              void* d_out, int out_size, void* d_ws, size_t ws_size,
                              hipStream_t stream) {
    const float* vect = (const float*)d_in[0];
    const int*   vals = (const int*)d_in[1];
    const float* W0 = (const float*)d_in[2];
    const float* b0 = (const float*)d_in[3];
    const float* W1 = (const float*)d_in[4];
    const float* b1 = (const float*)d_in[5];
    const float* W2 = (const float*)d_in[6];
    const float* b2 = (const float*)d_in[7];
    const float* W3 = (const float*)d_in[8];
    const float* b3 = (const float*)d_in[9];
    const float* W4 = (const float*)d_in[10];
    const float* b4 = (const float*)d_in[11];
    const float* W5 = (const float*)d_in[12];
    const float* b5 = (const float*)d_in[13];

    float* partials    = (float*)d_ws;                     // 2048*5*4 = 40 KB
    unsigned char* Wt  = (unsigned char*)d_ws + 131072;    // 4*256*256 = 256 KB
    float* out         = (float*)d_out;

    conv_w<<<1024, 64, 0, stream>>>(W1, W2, W3, W4, Wt);
    pinn_main<<<NBLK, 512, 0, stream>>>(vect, vals, W0, b0, b1, b2, b3,
                                        b4, W5, b5, Wt, partials);
    pinn_reduce<<<1, 256, 0, stream>>>(partials, out);
}

// Round 19
// 114.983 us; speedup vs baseline: 1.9984x; 1.9984x over previous
//
#include <hip/hip_runtime.h>

#define N_PTS   65536
#define PBLK    32                 // points per block
#define NBLK    (N_PTS / PBLK)     // 2048 blocks
#define HID     256
#define NCH     4                  // v, p=gx+gy, m=gx-gy, h=hxx+hyy

typedef __attribute__((ext_vector_type(16))) float floatx16;  // 32x32 MFMA C/D
typedef __attribute__((ext_vector_type(4)))  float floatx4;
typedef __attribute__((ext_vector_type(8)))  int   int8v;     // 32-byte fp8 frag
typedef __attribute__((ext_vector_type(4)))  long long llx4;  // 32-byte as 4x b64
typedef __attribute__((ext_vector_type(2)))  unsigned uint2v;

// Pade(3,2)+clamp tanh: 5 VALU + 1 TRANS. |err| <= ~7e-4 abs; exact saturation.
__device__ __forceinline__ float fast_tanh(float x) {
    float x2  = x * x;
    float num = x * (27.0f + x2);
    float den = 27.0f + 9.0f * x2;
    float r   = num * __builtin_amdgcn_rcpf(den);
    return fminf(fmaxf(r, -1.0f), 1.0f);   // -> v_med3_f32
}
__device__ __forceinline__ floatx4 tanh4(floatx4 z) {
    floatx4 r;
    r.x = fast_tanh(z.x); r.y = fast_tanh(z.y);
    r.z = fast_tanh(z.z); r.w = fast_tanh(z.w);
    return r;
}
// pack 4 f32 -> 4 fp8(e4m3) in one 32-bit word (2 cvt_pk instrs)
__device__ __forceinline__ unsigned pk4_fp8(floatx4 v) {
    unsigned w = __builtin_amdgcn_cvt_pk_fp8_f32(v.x, v.y, 0, false);
    w = __builtin_amdgcn_cvt_pk_fp8_f32(v.z, v.w, (int)w, true);
    return w;
}
__device__ __forceinline__ unsigned pk4_fp8s(float a, float b, float c, float d) {
    unsigned w = __builtin_amdgcn_cvt_pk_fp8_f32(a, b, 0, false);
    w = __builtin_amdgcn_cvt_pk_fp8_f32(c, d, (int)w, true);
    return w;
}

// ---- weight transpose+convert: Wt[L][n][k] = fp8(W_L[k][n]) ----
__global__ __launch_bounds__(64) void conv_w(
    const float* __restrict__ W1, const float* __restrict__ W2,
    const float* __restrict__ W3, const float* __restrict__ W4,
    unsigned char* __restrict__ Wt)
{
    int layer = blockIdx.x >> 8;
    int n     = blockIdx.x & 255;
    const float* W = (layer == 0) ? W1 : (layer == 1) ? W2 : (layer == 2) ? W3 : W4;
    int t = threadIdx.x;                      // word index: k = 4t..4t+3
    float a = W[(t * 4 + 0) * 256 + n];
    float b = W[(t * 4 + 1) * 256 + n];
    float c = W[(t * 4 + 2) * 256 + n];
    float d = W[(t * 4 + 3) * 256 + n];
    ((unsigned*)Wt)[((layer << 8) + n) * 64 + t] = pk4_fp8s(a, b, c, d);
}

__global__ __launch_bounds__(512, 4) void pinn_main(
    const float* __restrict__ vect, const int* __restrict__ vals,
    const float* __restrict__ W0, const float* __restrict__ b0,
    const float* __restrict__ b1, const float* __restrict__ b2,
    const float* __restrict__ b3, const float* __restrict__ b4,
    const float* __restrict__ W5, const float* __restrict__ b5,
    const unsigned char* __restrict__ Wt, float* __restrict__ partials)
{
    // Hs[buf][ch][pt][k] fp8: byte = buf*32768 + ch*8192 + pt*256 + (k ^ ((pt&15)<<3))
    __shared__ __align__(16) unsigned char Hs[2][NCH][PBLK][HID];   // 64 KB
    __shared__ float redT[8][PBLK];   // per-wave partial T dot
    __shared__ float redR[8][PBLK];   // per-wave partial R dot

    const int tid   = threadIdx.x;
    const int wave  = tid >> 6;
    const int lane  = tid & 63;
    const int pt    = lane & 31;          // MFMA column = point / A row
    const int hi    = lane >> 5;
    const int pbase = blockIdx.x * PBLK;
    const int swz   = (pt & 15) << 3;     // 8B-granular XOR swizzle (2-way = free)

    // ---------------- layer 0: 2 -> 256 (fp32 VALU) ----------------
    {
        const int p0 = tid & 31;          // point
        const int c0 = (tid >> 5) * 16;   // 16 neurons per thread
        const int sz = (p0 & 15) << 3;
        float x = vect[(pbase + p0) * 2 + 0];
        float y = vect[(pbase + p0) * 2 + 1];
        #pragma unroll
        for (int jj = 0; jj < 2; ++jj) {
            const int cb = c0 + jj * 8;
            float4 wxa = *(const float4*)(W0 + cb);
            float4 wxb = *(const float4*)(W0 + cb + 4);
            float4 wya = *(const float4*)(W0 + HID + cb);
            float4 wyb = *(const float4*)(W0 + HID + cb + 4);
            float4 bba = *(const float4*)(b0 + cb);
            float4 bbb = *(const float4*)(b0 + cb + 4);
            float wx[8] = {wxa.x, wxa.y, wxa.z, wxa.w, wxb.x, wxb.y, wxb.z, wxb.w};
            float wy[8] = {wya.x, wya.y, wya.z, wya.w, wyb.x, wyb.y, wyb.z, wyb.w};
            float bb[8] = {bba.x, bba.y, bba.z, bba.w, bbb.x, bbb.y, bbb.z, bbb.w};
            float av[8], pv[8], mv[8], hv[8];
            #pragma unroll
            for (int q = 0; q < 8; ++q) {
                float z  = x * wx[q] + y * wy[q] + bb[q];
                float a  = fast_tanh(z);
                float s  = 1.0f - a * a;
                float gx = s * wx[q];
                float gy = s * wy[q];
                av[q] = a;
                pv[q] = gx + gy;
                mv[q] = gx - gy;
                hv[q] = -2.0f * a * (gx * wx[q] + gy * wy[q]);
            }
            const int idx = p0 * 256 + (cb ^ sz);
            *(uint2v*)&Hs[0][0][0][idx] = (uint2v){pk4_fp8s(av[0],av[1],av[2],av[3]),
                                                   pk4_fp8s(av[4],av[5],av[6],av[7])};
            *(uint2v*)&Hs[0][1][0][idx] = (uint2v){pk4_fp8s(pv[0],pv[1],pv[2],pv[3]),
                                                   pk4_fp8s(pv[4],pv[5],pv[6],pv[7])};
            *(uint2v*)&Hs[0][2][0][idx] = (uint2v){pk4_fp8s(mv[0],mv[1],mv[2],mv[3]),
                                                   pk4_fp8s(mv[4],mv[5],mv[6],mv[7])};
            *(uint2v*)&Hs[0][3][0][idx] = (uint2v){pk4_fp8s(hv[0],hv[1],hv[2],hv[3]),
                                                   pk4_fp8s(hv[4],hv[5],hv[6],hv[7])};
        }
    }
    __syncthreads();

    // ---------------- hidden layers 1..3: MX-scaled 32x32x64 fp8 MFMA ----------------
    const float* bs[3] = {b1, b2, b3};

    floatx16 zk = (floatx16)(0.0f);       // zero C-operand, init once

    #pragma unroll
    for (int L = 0; L < 3; ++L) {
        const int cur = L & 1;
        const int nxt = cur ^ 1;
        floatx16 acc[NCH];

        const unsigned char* wb = Wt + L * 65536 + (((wave << 5) + pt) << 8) + (hi << 5);
        const unsigned char* hb = &Hs[cur][0][pt][0];     // ch stride 8192

        __builtin_amdgcn_s_setprio(1);
        #pragma unroll
        for (int ks4 = 0; ks4 < 4; ++ks4) {
            const int kb = ks4 * 64 + (hi << 5);
            int8v af = *(const int8v*)(wb + ks4 * 64);    // direct 32B load
            const unsigned char* a0 = hb + ((kb +  0) ^ swz);
            const unsigned char* a1 = hb + ((kb +  8) ^ swz);
            const unsigned char* a2 = hb + ((kb + 16) ^ swz);
            const unsigned char* a3 = hb + ((kb + 24) ^ swz);
            #pragma unroll
            for (int ch = 0; ch < NCH; ++ch) {
                const int co = ch * 8192;
                llx4 t;
                t[0] = *(const long long*)(a0 + co);
                t[1] = *(const long long*)(a1 + co);
                t[2] = *(const long long*)(a2 + co);
                t[3] = *(const long long*)(a3 + co);
                int8v bfv = __builtin_bit_cast(int8v, t);
                acc[ch] = __builtin_amdgcn_mfma_scale_f32_32x32x64_f8f6f4(
                    af, bfv, (ks4 == 0) ? zk : acc[ch], 0, 0, 0, 0x7F, 0, 0x7F);
            }
        }
        __builtin_amdgcn_s_setprio(0);

        // epilogue (writes go to the other buffer; single barrier per layer)
        unsigned char* hw = &Hs[nxt][0][pt][0];
        #pragma unroll
        for (int q = 0; q < 4; ++q) {
            const int nq = (wave << 5) + q * 8 + hi * 4;
            floatx4 bb = *(const floatx4*)(bs[L] + nq);
            floatx4 z, zp, zm, zh;
            #pragma unroll
            for (int r = 0; r < 4; ++r) {
                const int reg = q * 4 + r;
                z[r]  = acc[0][reg];
                zp[r] = acc[1][reg];
                zm[r] = acc[2][reg];
                zh[r] = acc[3][reg];
            }
            z += bb;
            floatx4 a  = tanh4(z);
            floatx4 s  = 1.0f - a * a;
            floatx4 pv = s * zp;
            floatx4 mv = s * zm;
            floatx4 hv = s * (zh - a * (zp * zp + zm * zm));
            const int kk = nq ^ swz;
            *(unsigned*)(hw + 0 * 8192 + kk) = pk4_fp8(a);
            *(unsigned*)(hw + 1 * 8192 + kk) = pk4_fp8(pv);
            *(unsigned*)(hw + 2 * 8192 + kk) = pk4_fp8(mv);
            *(unsigned*)(hw + 3 * 8192 + kk) = pk4_fp8(hv);
        }
        __syncthreads();   // one barrier per layer
    }

    // ---------------- layer 4 (peeled): MFMA + FUSED final-layer dot ----------------
    {
        floatx16 acc[NCH];
        const unsigned char* wb = Wt + 3 * 65536 + (((wave << 5) + pt) << 8) + (hi << 5);
        const unsigned char* hb = &Hs[1][0][pt][0];       // cur = 3&1 = 1

        __builtin_amdgcn_s_setprio(1);
        #pragma unroll
        for (int ks4 = 0; ks4 < 4; ++ks4) {
            const int kb = ks4 * 64 + (hi << 5);
            int8v af = *(const int8v*)(wb + ks4 * 64);
            const unsigned char* a0 = hb + ((kb +  0) ^ swz);
            const unsigned char* a1 = hb + ((kb +  8) ^ swz);
            const unsigned char* a2 = hb + ((kb + 16) ^ swz);
            const unsigned char* a3 = hb + ((kb + 24) ^ swz);
            #pragma unroll
            for (int ch = 0; ch < NCH; ++ch) {
                const int co = ch * 8192;
                llx4 t;
                t[0] = *(const long long*)(a0 + co);
                t[1] = *(const long long*)(a1 + co);
                t[2] = *(const long long*)(a2 + co);
                t[3] = *(const long long*)(a3 + co);
                int8v bfv = __builtin_bit_cast(int8v, t);
                acc[ch] = __builtin_amdgcn_mfma_scale_f32_32x32x64_f8f6f4(
                    af, bfv, (ks4 == 0) ? zk : acc[ch], 0, 0, 0, 0x7F, 0, 0x7F);
            }
        }
        __builtin_amdgcn_s_setprio(0);

        // fused epilogue: activation + Hessian + dot with W5, all in-register
        float sT = 0.f, sR = 0.f;
        #pragma unroll
        for (int q = 0; q < 4; ++q) {
            const int nq = (wave << 5) + q * 8 + hi * 4;
            floatx4 bb = *(const floatx4*)(b4 + nq);
            floatx4 w5 = *(const floatx4*)(W5 + nq);
            floatx4 z, zp, zm, zh;
            #pragma unroll
            for (int r = 0; r < 4; ++r) {
                const int reg = q * 4 + r;
                z[r]  = acc[0][reg];
                zp[r] = acc[1][reg];
                zm[r] = acc[2][reg];
                zh[r] = acc[3][reg];
            }
            z += bb;
            floatx4 a  = tanh4(z);
            floatx4 s  = 1.0f - a * a;
            floatx4 hv = s * (zh - a * (zp * zp + zm * zm));
            sT += a.x * w5.x + a.y * w5.y + a.z * w5.z + a.w * w5.w;
            sR += hv.x * w5.x + hv.y * w5.y + hv.z * w5.z + hv.w * w5.w;
        }
        // combine hi=0 / hi=1 halves (lanes pt and pt+32)
        sT += __shfl_down(sT, 32, 64);
        sR += __shfl_down(sR, 32, 64);
        if (lane < 32) {
            redT[wave][lane] = sT;
            redR[wave][lane] = sR;
        }
    }
    __syncthreads();

    // ---------------- loss terms (wave 0) ----------------
    if (wave == 0) {
        const int p32 = lane & 31;
        float r0 = 0.f, r1 = 0.f, r2 = 0.f, r3 = 0.f, r4 = 0.f;
        if (lane < 32) {
            float T = b5[0];
            float R = 0.f;
            #pragma unroll
            for (int w = 0; w < 8; ++w) {
                T += redT[w][p32];
                R += redR[w][p32];
            }
            r0 = R * R;
            int m = vals[pbase + p32];
            if (m == 1)      { float d = T - 1200.0f; r1 = d * d; r2 = 1.0f; }
            else if (m == 2) { float d = T - 25.0f;   r3 = d * d; r4 = 1.0f; }
        }
        #pragma unroll
        for (int off = 32; off > 0; off >>= 1) {
            r0 += __shfl_down(r0, off, 64);
            r1 += __shfl_down(r1, off, 64);
            r2 += __shfl_down(r2, off, 64);
            r3 += __shfl_down(r3, off, 64);
            r4 += __shfl_down(r4, off, 64);
        }
        if (lane == 0) {
            partials[blockIdx.x * 5 + 0] = r0;
            partials[blockIdx.x * 5 + 1] = r1;
            partials[blockIdx.x * 5 + 2] = r2;
            partials[blockIdx.x * 5 + 3] = r3;
            partials[blockIdx.x * 5 + 4] = r4;
        }
    }
}

__global__ __launch_bounds__(256) void pinn_reduce(const float* __restrict__ p,
                                                   float* __restrict__ out)
{
    float s[5] = {0.f, 0.f, 0.f, 0.f, 0.f};
    for (int idx = threadIdx.x; idx < NBLK; idx += 256) {
        #pragma unroll
        for (int c = 0; c < 5; ++c) s[c] += p[idx * 5 + c];
    }
    #pragma unroll
    for (int c = 0; c < 5; ++c) {
        #pragma unroll
        for (int off = 32; off > 0; off >>= 1)
            s[c] += __shfl_down(s[c], off, 64);
    }
    __shared__ float r[4][5];
    int wave = threadIdx.x >> 6;
    int lane = threadIdx.x & 63;
    if (lane == 0) {
        #pragma unroll
        for (int c = 0; c < 5; ++c) r[wave][c] = s[c];
    }
    __syncthreads();
    if (threadIdx.x == 0) {
        float t[5];
        #pragma unroll
        for (int c = 0; c < 5; ++c) t[c] = r[0][c] + r[1][c] + r[2][c] + r[3][c];
        out[0] = t[0] / (float)N_PTS
               + t[1] / fmaxf(t[2], 1.0f)
               + t[3] / fmaxf(t[4], 1.0f);
    }
}

extern "C" void kernel_launch(void* const* d_in, const int* in_sizes, int n_in,
                              void* d_out, int out_size, void* d_ws, size_t ws_size,
                              hipStream_t stream) {
    const float* vect = (const float*)d_in[0];
    const int*   vals = (const int*)d_in[1];
    const float* W0 = (const float*)d_in[2];
    const float* b0 = (const float*)d_in[3];
    const float* W1 = (const float*)d_in[4];
    const float* b1 = (const float*)d_in[5];
    const float* W2 = (const float*)d_in[6];
    const float* b2 = (const float*)d_in[7];
    const float* W3 = (const float*)d_in[8];
    const float* b3 = (const float*)d_in[9];
    const float* W4 = (const float*)d_in[10];
    const float* b4 = (const float*)d_in[11];
    const float* W5 = (const float*)d_in[12];
    const float* b5 = (const float*)d_in[13];

    float* partials    = (float*)d_ws;                     // 2048*5*4 = 40 KB
    unsigned char* Wt  = (unsigned char*)d_ws + 131072;    // 4*256*256 = 256 KB
    float* out         = (float*)d_out;

    conv_w<<<1024, 64, 0, stream>>>(W1, W2, W3, W4, Wt);
    pinn_main<<<NBLK, 512, 0, stream>>>(vect, vals, W0, b0, b1, b2, b3,
                                        b4, W5, b5, Wt, partials);
    pinn_reduce<<<1, 256, 0, stream>>>(partials, out);
}